// Round 4
// baseline (87.905 us; speedup 1.0000x reference)
//
#include <hip/hip_runtime.h>
#include <hip/hip_bf16.h>
#include <math.h>

#define BB 64
#define CC 3
#define HH 384
#define WW 384
#define HW (HH * WW)

// Each block: one (image, channel, 64x16 tile), staged via LDS.
#define TILE_W 64
#define TILE_H 16
#define TX_TILES (WW / TILE_W)                 // 6
#define TY_TILES (HH / TILE_H)                 // 24
#define TILES_PER_IMG (TX_TILES * TY_TILES)    // 144
#define NBLOCKS (BB * CC * TILES_PER_IMG)      // 27648 (divisible by 8)

// Rotated bbox of a 64x16 tile at <=15deg: x-span <= 69, y-span <= 35.
// Odd row stride (71) decorrelates LDS banks between rows (71 % 32 = 7).
#define LW_STRIDE 71
#define LH_MAX 36
// LDS = 36 * 71 * 4 = 10224 B -> wave-cap limited: 8 blocks/CU = 32 waves (full)

__global__ __launch_bounds__(256, 8) void GeometricAugment_kernel(
    const float* __restrict__ x,
    const float* __restrict__ angles,
    const float* __restrict__ dx,
    const float* __restrict__ dy,
    float* __restrict__ out) {

    __shared__ float lds[LH_MAX * LW_STRIDE];

    // XCD-chunked bijective swizzle (27648 % 8 == 0)
    int bid = blockIdx.x;
    int swz = (bid & 7) * (NBLOCKS / 8) + (bid >> 3);

    // decompose: tile index fastest -> adjacent blocks share halo rows in L2
    int b   = swz / (CC * TILES_PER_IMG);
    int rem = swz - b * (CC * TILES_PER_IMG);
    int c   = rem / TILES_PER_IMG;
    int t   = rem - c * TILES_PER_IMG;
    int tyb = t / TX_TILES;
    int txb = t - tyb * TX_TILES;

    int tid = threadIdx.x;
    int tx  = tid & 63;   // 0..63
    int tyl = tid >> 6;   // 0..3

    const int X0 = txb * TILE_W;
    const int Y0 = tyb * TILE_H;

    const float cx = (WW - 1) * 0.5f;
    const float cy = (HH - 1) * 0.5f;

    float rad = angles[b] * (float)(M_PI / 180.0);
    float si, co;
    __sincosf(rad, &si, &co);
    float txs = dx[b];
    float tys = dy[b];

    // tile-corner sample coords (uniform across block)
    float xo0 = (float)X0 - cx - txs;
    float xo1 = (float)(X0 + TILE_W - 1) - cx - txs;
    float yo0 = (float)Y0 - cy - tys;
    float yo1 = (float)(Y0 + TILE_H - 1) - cy - tys;

    float xsA = co * xo0 + si * yo0 + cx;
    float xsB = co * xo1 + si * yo0 + cx;
    float xsC = co * xo0 + si * yo1 + cx;
    float xsD = co * xo1 + si * yo1 + cx;
    float ysA = -si * xo0 + co * yo0 + cy;
    float ysB = -si * xo1 + co * yo0 + cy;
    float ysC = -si * xo0 + co * yo1 + cy;
    float ysD = -si * xo1 + co * yo1 + cy;

    float xsmin = fminf(fminf(xsA, xsB), fminf(xsC, xsD));
    float xsmax = fmaxf(fmaxf(xsA, xsB), fmaxf(xsC, xsD));
    float ysmin = fminf(fminf(ysA, ysB), fminf(ysC, ysD));
    float ysmax = fmaxf(fmaxf(ysA, ysB), fmaxf(ysC, ysD));

    int ximin = (int)floorf(xsmin) - 1;
    int yimin = (int)floorf(ysmin) - 1;
    int LW = (int)floorf(xsmax) + 2 - ximin + 1;  // <= 69
    int LH = (int)floorf(ysmax) + 2 - yimin + 1;  // <= 35
    LW = min(LW, LW_STRIDE);
    LH = min(LH, LH_MAX);

    const float* img = x + ((size_t)b * CC + c) * HW;

    // ---- stage bbox into LDS (coalesced rows, clamped addressing) ----
    for (int y = tyl; y < LH; y += 4) {
        int gy = min(max(yimin + y, 0), HH - 1);
        const float* row = img + gy * WW;
        for (int xL = tx; xL < LW; xL += 64) {
            int gx = min(max(ximin + xL, 0), WW - 1);
            lds[y * LW_STRIDE + xL] = row[gx];
        }
    }
    __syncthreads();

    // ---- gather from LDS ----
    int x_out = X0 + tx;
    float xo = (float)x_out - cx - txs;

    float* outb = out + ((size_t)b * CC + c) * HW + (size_t)Y0 * WW + x_out;

    #pragma unroll
    for (int r = 0; r < TILE_H / 4; ++r) {
        int y_out = Y0 + tyl + r * 4;
        float yo = (float)y_out - cy - tys;

        float xs =  co * xo + si * yo + cx;
        float ys = -si * xo + co * yo + cy;

        float x0f = floorf(xs);
        float y0f = floorf(ys);
        float wx = xs - x0f;
        float wy = ys - y0f;
        int x0 = (int)x0f;
        int y0 = (int)y0f;
        int x1 = x0 + 1;
        int y1 = y0 + 1;

        float vx0 = (x0 >= 0 && x0 < WW) ? 1.0f : 0.0f;
        float vx1 = (x1 >= 0 && x1 < WW) ? 1.0f : 0.0f;
        float vy0 = (y0 >= 0 && y0 < HH) ? 1.0f : 0.0f;
        float vy1 = (y1 >= 0 && y1 < HH) ? 1.0f : 0.0f;

        float w00 = (1.0f - wx) * (1.0f - wy) * vx0 * vy0;
        float w01 = wx * (1.0f - wy) * vx1 * vy0;
        float w10 = (1.0f - wx) * wy * vx0 * vy1;
        float w11 = wx * wy * vx1 * vy1;

        int xL0 = x0 - ximin;   // in [1, LW-2] by construction
        int yL0 = y0 - yimin;

        const float* l = lds + yL0 * LW_STRIDE + xL0;
        float v00 = l[0];
        float v01 = l[1];
        float v10 = l[LW_STRIDE];
        float v11 = l[LW_STRIDE + 1];
        float v = v00 * w00 + v01 * w01 + v10 * w10 + v11 * w11;
        v = fminf(fmaxf(v, 0.0f), 1.0f);
        __builtin_nontemporal_store(v, outb + (size_t)(tyl + r * 4) * WW);
    }
}

extern "C" void kernel_launch(void* const* d_in, const int* in_sizes, int n_in,
                              void* d_out, int out_size, void* d_ws, size_t ws_size,
                              hipStream_t stream) {
    const float* x      = (const float*)d_in[0];
    const float* angles = (const float*)d_in[1];
    const float* dx     = (const float*)d_in[2];
    const float* dy     = (const float*)d_in[3];
    float* out = (float*)d_out;

    GeometricAugment_kernel<<<NBLOCKS, 256, 0, stream>>>(x, angles, dx, dy, out);
}

// Round 5
// 42.125 us; speedup vs baseline: 2.0868x; 2.0868x over previous
//
#include <hip/hip_runtime.h>
#include <hip/hip_bf16.h>
#include <math.h>

#define BB 64
#define CC 3
#define HH 384
#define WW 384
#define HW (HH * WW)

// Each block: 64x16 output tile of one image (all 3 channels), staged via LDS.
// 512 threads = 64(x) x 8(y); each thread does 2 rows (stride 8).
#define TILE_W 64
#define TILE_H 16
#define TX_TILES (WW / TILE_W)                 // 6
#define TY_TILES (HH / TILE_H)                 // 24
#define TILES_PER_IMG (TX_TILES * TY_TILES)    // 144
#define NBLOCKS (BB * TILES_PER_IMG)           // 9216 (divisible by 8)

// Rotated bbox of 64x16 at <=15deg: x floor-span+4 <= 69, y floor-span+4 <= 35.
// ODD row stride (71) -> successive rows shift banks by 7: decorrelated.
#define LW_STRIDE 71
#define LH_MAX 36
// LDS = 3 * 36 * 71 * 4 = 30672 B -> 4 blocks/CU x 8 waves = 32 waves (100%)

__global__ __launch_bounds__(512, 8) void GeometricAugment_kernel(
    const float* __restrict__ x,
    const float* __restrict__ angles,
    const float* __restrict__ dx,
    const float* __restrict__ dy,
    float* __restrict__ out) {

    __shared__ float lds[CC * LH_MAX * LW_STRIDE];

    // XCD-chunked bijective swizzle (9216 % 8 == 0)
    int bid = blockIdx.x;
    int swz = (bid & 7) * (NBLOCKS / 8) + (bid >> 3);

    int b   = swz / TILES_PER_IMG;
    int t   = swz - b * TILES_PER_IMG;
    int tyb = t / TX_TILES;
    int txb = t - tyb * TX_TILES;

    int tid = threadIdx.x;
    int tx  = tid & 63;   // 0..63
    int tyl = tid >> 6;   // 0..7

    const int X0 = txb * TILE_W;
    const int Y0 = tyb * TILE_H;

    const float cx = (WW - 1) * 0.5f;
    const float cy = (HH - 1) * 0.5f;

    float rad = angles[b] * (float)(M_PI / 180.0);
    float si, co;
    __sincosf(rad, &si, &co);
    float txs = dx[b];
    float tys = dy[b];

    // tile-corner sample coords (uniform across block)
    float xo0 = (float)X0 - cx - txs;
    float xo1 = (float)(X0 + TILE_W - 1) - cx - txs;
    float yo0 = (float)Y0 - cy - tys;
    float yo1 = (float)(Y0 + TILE_H - 1) - cy - tys;

    float xsA = co * xo0 + si * yo0 + cx;
    float xsB = co * xo1 + si * yo0 + cx;
    float xsC = co * xo0 + si * yo1 + cx;
    float xsD = co * xo1 + si * yo1 + cx;
    float ysA = -si * xo0 + co * yo0 + cy;
    float ysB = -si * xo1 + co * yo0 + cy;
    float ysC = -si * xo0 + co * yo1 + cy;
    float ysD = -si * xo1 + co * yo1 + cy;

    float xsmin = fminf(fminf(xsA, xsB), fminf(xsC, xsD));
    float xsmax = fmaxf(fmaxf(xsA, xsB), fmaxf(xsC, xsD));
    float ysmin = fminf(fminf(ysA, ysB), fminf(ysC, ysD));
    float ysmax = fmaxf(fmaxf(ysA, ysB), fmaxf(ysC, ysD));

    int ximin = (int)floorf(xsmin) - 1;
    int yimin = (int)floorf(ysmin) - 1;
    int LH = (int)floorf(ysmax) + 2 - yimin + 1;  // <= 35
    LH = min(LH, LH_MAX);

    const float* imgb = x + (size_t)b * CC * HW;

    // ---- stage bbox into LDS: flat loop, full 71-wide rows (clamped) ----
    // i -> (y = i/71, xL = i%71); compile-time divisor -> magic-mul.
    int nelem = LH * LW_STRIDE;
    for (int i = tid; i < nelem; i += 512) {
        int y  = i / LW_STRIDE;
        int xL = i - y * LW_STRIDE;
        int gy = min(max(yimin + y, 0), HH - 1);
        int gx = min(max(ximin + xL, 0), WW - 1);
        const float* src = imgb + gy * WW + gx;
        #pragma unroll
        for (int c = 0; c < CC; ++c) {
            lds[c * (LH_MAX * LW_STRIDE) + i] = src[c * HW];
        }
    }
    __syncthreads();

    // ---- gather from LDS ----
    int x_out = X0 + tx;
    float xo = (float)x_out - cx - txs;

    float* outb = out + (size_t)b * CC * HW + (size_t)Y0 * WW + x_out;

    #pragma unroll
    for (int r = 0; r < TILE_H / 8; ++r) {
        int yrow = tyl + r * 8;
        float yo = (float)(Y0 + yrow) - cy - tys;

        float xs =  co * xo + si * yo + cx;
        float ys = -si * xo + co * yo + cy;

        float x0f = floorf(xs);
        float y0f = floorf(ys);
        float wx = xs - x0f;
        float wy = ys - y0f;
        int x0 = (int)x0f;
        int y0 = (int)y0f;
        int x1 = x0 + 1;
        int y1 = y0 + 1;

        float vx0 = (x0 >= 0 && x0 < WW) ? 1.0f : 0.0f;
        float vx1 = (x1 >= 0 && x1 < WW) ? 1.0f : 0.0f;
        float vy0 = (y0 >= 0 && y0 < HH) ? 1.0f : 0.0f;
        float vy1 = (y1 >= 0 && y1 < HH) ? 1.0f : 0.0f;

        float w00 = (1.0f - wx) * (1.0f - wy) * vx0 * vy0;
        float w01 = wx * (1.0f - wy) * vx1 * vy0;
        float w10 = (1.0f - wx) * wy * vx0 * vy1;
        float w11 = wx * wy * vx1 * vy1;

        int xL0 = x0 - ximin;   // in [1, LW-2] by construction
        int yL0 = y0 - yimin;

        int base = yL0 * LW_STRIDE + xL0;

        #pragma unroll
        for (int c = 0; c < CC; ++c) {
            const float* l = lds + c * (LH_MAX * LW_STRIDE) + base;
            float v00 = l[0];
            float v01 = l[1];
            float v10 = l[LW_STRIDE];
            float v11 = l[LW_STRIDE + 1];
            float v = v00 * w00 + v01 * w01 + v10 * w10 + v11 * w11;
            v = fminf(fmaxf(v, 0.0f), 1.0f);
            __builtin_nontemporal_store(v, outb + (size_t)c * HW + (size_t)yrow * WW);
        }
    }
}

extern "C" void kernel_launch(void* const* d_in, const int* in_sizes, int n_in,
                              void* d_out, int out_size, void* d_ws, size_t ws_size,
                              hipStream_t stream) {
    const float* x      = (const float*)d_in[0];
    const float* angles = (const float*)d_in[1];
    const float* dx     = (const float*)d_in[2];
    const float* dy     = (const float*)d_in[3];
    float* out = (float*)d_out;

    GeometricAugment_kernel<<<NBLOCKS, 512, 0, stream>>>(x, angles, dx, dy, out);
}

// Round 6
// 39.832 us; speedup vs baseline: 2.2069x; 1.0576x over previous
//
#include <hip/hip_runtime.h>
#include <hip/hip_bf16.h>
#include <math.h>

#define BB 64
#define CC 3
#define HH 384
#define WW 384
#define HW (HH * WW)

// Each block: 64x24 output tile of one image (3 channels), staged via LDS.
// 512 threads = 64(x) x 8(y); each thread does 3 rows (stride 8).
#define TILE_W 64
#define TILE_H 24
#define TX_TILES (WW / TILE_W)                 // 6
#define TY_TILES (HH / TILE_H)                 // 16
#define TILES_PER_IMG (TX_TILES * TY_TILES)    // 96
#define NBLOCKS (BB * TILES_PER_IMG)           // 6144 (divisible by 8)

// Rotated bbox of 64x24 at <=15deg:
//   x floor-span <= 63*cos15+23*sin15 = 66.9 -> 67; +4 -> LW <= 71
//   y floor-span <= 63*sin15+23*cos15 = 38.6 -> 39; +4 -> LH <= 43
#define LW_STRIDE 71      // odd -> rows shift banks by 7
#define LH_MAX 43
#define LCH (LH_MAX * LW_STRIDE)
// LDS = 3 * 43 * 71 * 4 = 36636 B -> 4 blocks/CU x 8 waves = 32 waves (100%)

__global__ __launch_bounds__(512, 8) void GeometricAugment_kernel(
    const float* __restrict__ x,
    const float* __restrict__ angles,
    const float* __restrict__ dx,
    const float* __restrict__ dy,
    float* __restrict__ out) {

    __shared__ float lds[CC * LCH];

    // XCD-chunked bijective swizzle (6144 % 8 == 0)
    int bid = blockIdx.x;
    int swz = (bid & 7) * (NBLOCKS / 8) + (bid >> 3);

    int b   = swz / TILES_PER_IMG;
    int t   = swz - b * TILES_PER_IMG;
    int tyb = t / TX_TILES;
    int txb = t - tyb * TX_TILES;

    int tid = threadIdx.x;
    int tx  = tid & 63;   // 0..63
    int tyl = tid >> 6;   // 0..7

    const int X0 = txb * TILE_W;
    const int Y0 = tyb * TILE_H;

    const float cx = (WW - 1) * 0.5f;
    const float cy = (HH - 1) * 0.5f;

    float rad = angles[b] * (float)(M_PI / 180.0);
    float si, co;
    __sincosf(rad, &si, &co);
    float txs = dx[b];
    float tys = dy[b];

    // tile-corner sample coords (uniform across block)
    float xo0 = (float)X0 - cx - txs;
    float xo1 = (float)(X0 + TILE_W - 1) - cx - txs;
    float yo0 = (float)Y0 - cy - tys;
    float yo1 = (float)(Y0 + TILE_H - 1) - cy - tys;

    float xsA = co * xo0 + si * yo0 + cx;
    float xsB = co * xo1 + si * yo0 + cx;
    float xsC = co * xo0 + si * yo1 + cx;
    float xsD = co * xo1 + si * yo1 + cx;
    float ysA = -si * xo0 + co * yo0 + cy;
    float ysB = -si * xo1 + co * yo0 + cy;
    float ysC = -si * xo0 + co * yo1 + cy;
    float ysD = -si * xo1 + co * yo1 + cy;

    float xsmin = fminf(fminf(xsA, xsB), fminf(xsC, xsD));
    float xsmax = fmaxf(fmaxf(xsA, xsB), fmaxf(xsC, xsD));
    float ysmin = fminf(fminf(ysA, ysB), fminf(ysC, ysD));
    float ysmax = fmaxf(fmaxf(ysA, ysB), fmaxf(ysC, ysD));

    int ximin = (int)floorf(xsmin) - 1;
    int yimin = (int)floorf(ysmin) - 1;
    int LH = (int)floorf(ysmax) + 2 - yimin + 1;  // <= 43
    LH = min(LH, LH_MAX);

    // block-uniform interior test (full staged window of LW_STRIDE cols in-bounds)
    bool interior = (ximin >= 0) && (yimin >= 0) &&
                    (ximin + LW_STRIDE <= WW) && (yimin + LH <= HH);

    const float* imgb = x + (size_t)b * CC * HW;

    int nelem = LH * LW_STRIDE;
    if (interior) {
        // ---- fast staging: no clamps ----
        const float* srcb = imgb + yimin * WW + ximin;
        for (int i = tid; i < nelem; i += 512) {
            int y  = i / LW_STRIDE;
            int xL = i - y * LW_STRIDE;
            const float* src = srcb + y * WW + xL;
            #pragma unroll
            for (int c = 0; c < CC; ++c)
                lds[c * LCH + i] = src[c * HW];
        }
    } else {
        // ---- clamped staging ----
        for (int i = tid; i < nelem; i += 512) {
            int y  = i / LW_STRIDE;
            int xL = i - y * LW_STRIDE;
            int gy = min(max(yimin + y, 0), HH - 1);
            int gx = min(max(ximin + xL, 0), WW - 1);
            const float* src = imgb + gy * WW + gx;
            #pragma unroll
            for (int c = 0; c < CC; ++c)
                lds[c * LCH + i] = src[c * HW];
        }
    }
    __syncthreads();

    // ---- gather from LDS ----
    int x_out = X0 + tx;
    float xo = (float)x_out - cx - txs;
    float yo = (float)(Y0 + tyl) - cy - tys;

    float xs =  co * xo + si * yo + cx;
    float ys = -si * xo + co * yo + cy;
    const float dxs = 8.0f * si;
    const float dys = 8.0f * co;

    float* outb = out + (size_t)b * CC * HW + (size_t)Y0 * WW + x_out;

    if (interior) {
        #pragma unroll
        for (int r = 0; r < TILE_H / 8; ++r) {
            float x0f = floorf(xs);
            float y0f = floorf(ys);
            float wx = xs - x0f;
            float wy = ys - y0f;
            int base = ((int)y0f - yimin) * LW_STRIDE + ((int)x0f - ximin);

            #pragma unroll
            for (int c = 0; c < CC; ++c) {
                const float* l = lds + c * LCH + base;
                float v00 = l[0];
                float v01 = l[1];
                float v10 = l[LW_STRIDE];
                float v11 = l[LW_STRIDE + 1];
                float top = v00 + wx * (v01 - v00);
                float bot = v10 + wx * (v11 - v10);
                float v = top + wy * (bot - top);
                v = fminf(fmaxf(v, 0.0f), 1.0f);
                __builtin_nontemporal_store(v, outb + (size_t)c * HW + (size_t)(tyl + r * 8) * WW);
            }
            xs += dxs;
            ys += dys;
        }
    } else {
        #pragma unroll
        for (int r = 0; r < TILE_H / 8; ++r) {
            float x0f = floorf(xs);
            float y0f = floorf(ys);
            float wx = xs - x0f;
            float wy = ys - y0f;
            int x0 = (int)x0f;
            int y0 = (int)y0f;
            int x1 = x0 + 1;
            int y1 = y0 + 1;

            float vx0 = (x0 >= 0 && x0 < WW) ? 1.0f : 0.0f;
            float vx1 = (x1 >= 0 && x1 < WW) ? 1.0f : 0.0f;
            float vy0 = (y0 >= 0 && y0 < HH) ? 1.0f : 0.0f;
            float vy1 = (y1 >= 0 && y1 < HH) ? 1.0f : 0.0f;

            float w00 = (1.0f - wx) * (1.0f - wy) * vx0 * vy0;
            float w01 = wx * (1.0f - wy) * vx1 * vy0;
            float w10 = (1.0f - wx) * wy * vx0 * vy1;
            float w11 = wx * wy * vx1 * vy1;

            int base = (y0 - yimin) * LW_STRIDE + (x0 - ximin);

            #pragma unroll
            for (int c = 0; c < CC; ++c) {
                const float* l = lds + c * LCH + base;
                float v00 = l[0];
                float v01 = l[1];
                float v10 = l[LW_STRIDE];
                float v11 = l[LW_STRIDE + 1];
                float v = v00 * w00 + v01 * w01 + v10 * w10 + v11 * w11;
                v = fminf(fmaxf(v, 0.0f), 1.0f);
                __builtin_nontemporal_store(v, outb + (size_t)c * HW + (size_t)(tyl + r * 8) * WW);
            }
            xs += dxs;
            ys += dys;
        }
    }
}

extern "C" void kernel_launch(void* const* d_in, const int* in_sizes, int n_in,
                              void* d_out, int out_size, void* d_ws, size_t ws_size,
                              hipStream_t stream) {
    const float* x      = (const float*)d_in[0];
    const float* angles = (const float*)d_in[1];
    const float* dx     = (const float*)d_in[2];
    const float* dy     = (const float*)d_in[3];
    float* out = (float*)d_out;

    GeometricAugment_kernel<<<NBLOCKS, 512, 0, stream>>>(x, angles, dx, dy, out);
}